// Round 6
// baseline (376.040 us; speedup 1.0000x reference)
//
#include <hip/hip_runtime.h>

#define N_NODES 50000
#define N_EDGES 800000
#define N_GRAPHS 256
#define NB_SCAN 196   // ceil(50000/256)

// ---------------------------------------------------------------------------
// Fused dense: HW1 = act(X) @ W1 ; AGG = act(X) @ W2 + b
// One GEMM with concatenated columns [W1 | W2]. 64x64 C-tile / block(256),
// K-tile <=64, A transposed in LDS (stride 68), 4x4 register micro-tile.
// Used for layers 2 and 3 (FIN > FOUT there, so post-projection gather wins).
// ---------------------------------------------------------------------------
template<int FIN, int FOUT>
__global__ __launch_bounds__(256)
void dense_kernel(const float* __restrict__ X, const float* __restrict__ W1,
                  const float* __restrict__ W2, const float* __restrict__ Bias,
                  float* __restrict__ HW1, float* __restrict__ AGG, int relu_in)
{
    constexpr int KT = (FIN > 64) ? 64 : FIN;
    __shared__ float As[KT * 68];
    __shared__ float Bs[KT * 64];

    const int tid = threadIdx.x;
    const int tm = tid & 15;
    const int tn = tid >> 4;
    const int m0 = blockIdx.x * 64;
    const int c0 = blockIdx.y * 64;

    float acc[4][4];
    #pragma unroll
    for (int i = 0; i < 4; ++i)
        #pragma unroll
        for (int j = 0; j < 4; ++j) acc[i][j] = 0.f;

    for (int kk = 0; kk < FIN; kk += KT) {
        for (int i = tid; i < 64 * KT; i += 256) {
            int n = i / KT;
            int k = i - n * KT;
            int gn = m0 + n;
            float v = 0.f;
            if (gn < N_NODES) v = X[gn * FIN + kk + k];
            if (relu_in) v = fmaxf(v, 0.f);
            As[k * 68 + n] = v;
        }
        for (int i = tid; i < 64 * KT; i += 256) {
            int k = i >> 6;
            int n = i & 63;
            int c = c0 + n;
            float w = (c < FOUT) ? W1[(kk + k) * FOUT + c]
                                 : W2[(kk + k) * FOUT + (c - FOUT)];
            Bs[k * 64 + n] = w;
        }
        __syncthreads();

        #pragma unroll 4
        for (int k = 0; k < KT; ++k) {
            const float4 a = *(const float4*)(As + k * 68 + 4 * tm);
            const float4 b = *(const float4*)(Bs + k * 64 + 4 * tn);
            float av[4] = {a.x, a.y, a.z, a.w};
            float bv[4] = {b.x, b.y, b.z, b.w};
            #pragma unroll
            for (int i = 0; i < 4; ++i)
                #pragma unroll
                for (int j = 0; j < 4; ++j)
                    acc[i][j] = fmaf(av[i], bv[j], acc[i][j]);
        }
        __syncthreads();
    }

    const int c = c0 + 4 * tn;
    const bool w2half = (c >= FOUT);
    float4 bias = make_float4(0.f, 0.f, 0.f, 0.f);
    if (w2half) bias = *(const float4*)(Bias + (c - FOUT));

    #pragma unroll
    for (int i = 0; i < 4; ++i) {
        int gm = m0 + 4 * tm + i;
        if (gm >= N_NODES) continue;
        float4 v = make_float4(acc[i][0] + bias.x, acc[i][1] + bias.y,
                               acc[i][2] + bias.z, acc[i][3] + bias.w);
        if (w2half)
            *(float4*)(AGG + (size_t)gm * FOUT + (c - FOUT)) = v;
        else
            *(float4*)(HW1 + (size_t)gm * FOUT + c) = v;
    }
}

// ---------------------------------------------------------------------------
// Layer-1 dense: h1 = CI @ Wc + b, CI = [A@X pad32 | X pad32] (N x 64),
// Wc row-split: rows 0..29 -> W1, rows 32..61 -> W2, pad rows -> 0.
// ---------------------------------------------------------------------------
__global__ __launch_bounds__(256)
void dense1_kernel(const float* __restrict__ CI, const float* __restrict__ W1,
                   const float* __restrict__ W2, const float* __restrict__ Bias,
                   float* __restrict__ H1)
{
    __shared__ float As[64 * 68];
    __shared__ float Bs[64 * 64];

    const int tid = threadIdx.x;
    const int tm = tid & 15;
    const int tn = tid >> 4;
    const int m0 = blockIdx.x * 64;
    const int c0 = blockIdx.y * 64;

    float acc[4][4];
    #pragma unroll
    for (int i = 0; i < 4; ++i)
        #pragma unroll
        for (int j = 0; j < 4; ++j) acc[i][j] = 0.f;

    for (int i = tid; i < 64 * 64; i += 256) {
        int n = i >> 6;
        int k = i & 63;
        int gn = m0 + n;
        As[k * 68 + n] = (gn < N_NODES) ? CI[(size_t)gn * 64 + k] : 0.f;
    }
    for (int i = tid; i < 64 * 64; i += 256) {
        int k = i >> 6;
        int n = i & 63;
        int c = c0 + n;
        float w = 0.f;
        if (k < 30)       w = W1[k * 128 + c];
        else if (k >= 32 && k < 62) w = W2[(k - 32) * 128 + c];
        Bs[k * 64 + n] = w;
    }
    __syncthreads();

    #pragma unroll 4
    for (int k = 0; k < 64; ++k) {
        const float4 a = *(const float4*)(As + k * 68 + 4 * tm);
        const float4 b = *(const float4*)(Bs + k * 64 + 4 * tn);
        float av[4] = {a.x, a.y, a.z, a.w};
        float bv[4] = {b.x, b.y, b.z, b.w};
        #pragma unroll
        for (int i = 0; i < 4; ++i)
            #pragma unroll
            for (int j = 0; j < 4; ++j)
                acc[i][j] = fmaf(av[i], bv[j], acc[i][j]);
    }

    const int c = c0 + 4 * tn;
    const float4 bias = *(const float4*)(Bias + c);
    #pragma unroll
    for (int i = 0; i < 4; ++i) {
        int gm = m0 + 4 * tm + i;
        if (gm >= N_NODES) continue;
        float4 v = make_float4(acc[i][0] + bias.x, acc[i][1] + bias.y,
                               acc[i][2] + bias.z, acc[i][3] + bias.w);
        *(float4*)(H1 + (size_t)gm * 128 + c) = v;
    }
}

// ---------------------------------------------------------------------------
// CSR build: histogram (4 edges/thread for atomic ILP)
// ---------------------------------------------------------------------------
__global__ __launch_bounds__(256)
void hist_kernel(const int* __restrict__ ER, int* __restrict__ deg)
{
    int base = blockIdx.x * 1024 + threadIdx.x;
    #pragma unroll
    for (int i = 0; i < 4; ++i) {
        int e = base + i * 256;
        if (e < N_EDGES) atomicAdd(&deg[ER[e]], 1);
    }
}

// --- 3-phase device-wide exclusive scan of deg -> rowptr (+ seed cursor) ---
__global__ __launch_bounds__(256)
void blocksum_kernel(const int* __restrict__ deg, int* __restrict__ bsum)
{
    __shared__ int red[4];
    int i = blockIdx.x * 256 + threadIdx.x;
    int v = (i < N_NODES) ? deg[i] : 0;
    #pragma unroll
    for (int off = 32; off; off >>= 1) v += __shfl_down(v, off, 64);
    if ((threadIdx.x & 63) == 0) red[threadIdx.x >> 6] = v;
    __syncthreads();
    if (threadIdx.x == 0) bsum[blockIdx.x] = red[0] + red[1] + red[2] + red[3];
}

__global__ __launch_bounds__(256)
void bscan_kernel(int* __restrict__ bsum)
{
    __shared__ int s[256];
    int t = threadIdx.x;
    int v = (t < NB_SCAN) ? bsum[t] : 0;
    s[t] = v;
    __syncthreads();
    for (int off = 1; off < 256; off <<= 1) {
        int u = (t >= off) ? s[t - off] : 0;
        __syncthreads();
        s[t] += u;
        __syncthreads();
    }
    if (t < NB_SCAN) bsum[t] = s[t] - v;      // exclusive
}

__global__ __launch_bounds__(256)
void rowptr_kernel(const int* __restrict__ deg, const int* __restrict__ bsum,
                   int* __restrict__ rowptr, int* __restrict__ cursor)
{
    __shared__ int s[256];
    int t = threadIdx.x;
    int i = blockIdx.x * 256 + t;
    int v = (i < N_NODES) ? deg[i] : 0;
    s[t] = v;
    __syncthreads();
    for (int off = 1; off < 256; off <<= 1) {
        int u = (t >= off) ? s[t - off] : 0;
        __syncthreads();
        s[t] += u;
        __syncthreads();
    }
    int excl = s[t] - v + bsum[blockIdx.x];
    if (i < N_NODES) { rowptr[i] = excl; cursor[i] = excl; }
    if (i == 0) rowptr[N_NODES] = N_EDGES;
}

// ---------------------------------------------------------------------------
// Scatter: 4 edges/thread (independent atomic round-trips), packed int2
// record (src, wt) -> single 8B random store per edge (halves write-amp).
// ---------------------------------------------------------------------------
__global__ __launch_bounds__(256)
void scatter_kernel(const int* __restrict__ ER, const int* __restrict__ EC,
                    const float* __restrict__ EW, int* __restrict__ cursor,
                    int2* __restrict__ packed)
{
    int base = blockIdx.x * 1024 + threadIdx.x;
    #pragma unroll
    for (int i = 0; i < 4; ++i) {
        int e = base + i * 256;
        if (e < N_EDGES) {
            int d = ER[e];
            int s = EC[e];
            float w = EW[e];
            int pos = atomicAdd(&cursor[d], 1);
            packed[pos] = make_int2(s, __float_as_int(w));
        }
    }
}

// ---------------------------------------------------------------------------
// pad_kernel: XP[n][c] = (c<30) ? x[n][c] : 0   (N x 32)
//             CI[n][32+c] = same                (X half of layer-1 GEMM input)
// ---------------------------------------------------------------------------
__global__ __launch_bounds__(256)
void pad_kernel(const float* __restrict__ X, float* __restrict__ XP,
                float* __restrict__ CI)
{
    int idx = blockIdx.x * 256 + threadIdx.x;
    int n = idx >> 5;
    int c = idx & 31;
    if (n >= N_NODES) return;
    float v = (c < 30) ? X[n * 30 + c] : 0.f;
    XP[(size_t)n * 32 + c] = v;
    CI[(size_t)n * 64 + 32 + c] = v;
}

// ---------------------------------------------------------------------------
// aggx_kernel: CI[n][0..31] = sum_j w_j * XP[src_j][0..31]  (A @ X)
// ---------------------------------------------------------------------------
__global__ __launch_bounds__(256)
void aggx_kernel(const float* __restrict__ XP, const int* __restrict__ rowptr,
                 const int2* __restrict__ packed, float* __restrict__ CI)
{
    int tid = threadIdx.x;
    int local = tid >> 3;
    int q = tid & 7;
    int n = blockIdx.x * 32 + local;
    if (n >= N_NODES) return;
    int r0 = rowptr[n], r1 = rowptr[n + 1];
    float4 acc = make_float4(0.f, 0.f, 0.f, 0.f);
    for (int j = r0; j < r1; ++j) {
        int2 r = packed[j];
        float w = __int_as_float(r.y);
        const float4 h = *(const float4*)(XP + (size_t)r.x * 32 + q * 4);
        acc.x = fmaf(w, h.x, acc.x);
        acc.y = fmaf(w, h.y, acc.y);
        acc.z = fmaf(w, h.z, acc.z);
        acc.w = fmaf(w, h.w, acc.w);
    }
    *(float4*)(CI + (size_t)n * 64 + q * 4) = acc;
}

// ---------------------------------------------------------------------------
// Atomic-free SpMM (layers 2,3): group of FOUT/4 lanes owns dest node n,
// walks CSR, accumulates on top of AGG (= xW2+b), one store.
// ---------------------------------------------------------------------------
template<int FOUT>
__global__ __launch_bounds__(256)
void spmm_kernel(const float* __restrict__ HW1, const int* __restrict__ rowptr,
                 const int2* __restrict__ packed, float* __restrict__ AGG)
{
    constexpr int T = FOUT / 4;
    constexpr int NPB = 256 / T;
    int tid = threadIdx.x;
    int local = tid / T;
    int q = tid % T;
    int n = blockIdx.x * NPB + local;
    if (n >= N_NODES) return;
    int r0 = rowptr[n], r1 = rowptr[n + 1];
    float4 acc = *(const float4*)(AGG + (size_t)n * FOUT + q * 4);
    for (int j = r0; j < r1; ++j) {
        int2 r = packed[j];
        float w = __int_as_float(r.y);
        const float4 h = *(const float4*)(HW1 + (size_t)r.x * FOUT + q * 4);
        acc.x = fmaf(w, h.x, acc.x);
        acc.y = fmaf(w, h.y, acc.y);
        acc.z = fmaf(w, h.z, acc.z);
        acc.w = fmaf(w, h.w, acc.w);
    }
    *(float4*)(AGG + (size_t)n * FOUT + q * 4) = acc;
}

// ---------------------------------------------------------------------------
// Graph boundaries from sorted seg: start[g] = first node with seg >= g.
// ---------------------------------------------------------------------------
__global__ __launch_bounds__(256)
void bounds_kernel(const int* __restrict__ SEG, int* __restrict__ start)
{
    int n = blockIdx.x * 256 + threadIdx.x;
    if (n >= N_NODES) return;
    int g = SEG[n];
    int gprev = (n == 0) ? -1 : SEG[n - 1];
    for (int gg = gprev + 1; gg <= g; ++gg) start[gg] = n;
    if (n == N_NODES - 1)
        for (int gg = g + 1; gg <= N_GRAPHS; ++gg) start[gg] = N_NODES;
}

// ---------------------------------------------------------------------------
// Atomic-free pool: one block per graph; register accumulate relu(H),
// LDS-reduce, write pooled MEAN.
// ---------------------------------------------------------------------------
__global__ __launch_bounds__(256)
void pool_kernel(const float* __restrict__ H, const int* __restrict__ start,
                 float* __restrict__ POOLED)
{
    __shared__ float red[8][33];
    int g = blockIdx.x;
    int s = start[g], e = start[g + 1];
    int q = threadIdx.x & 31;
    int lane = threadIdx.x >> 5;
    float acc = 0.f;
    for (int n = s + lane; n < e; n += 8)
        acc += fmaxf(H[(size_t)n * 32 + q], 0.f);
    red[lane][q] = acc;
    __syncthreads();
    if (threadIdx.x < 32) {
        float v = 0.f;
        #pragma unroll
        for (int i = 0; i < 8; ++i) v += red[i][q];
        float inv = (e > s) ? 1.0f / (float)(e - s) : 1.0f;
        POOLED[g * 32 + q] = v * inv;
    }
}

// ---------------------------------------------------------------------------
// Head: softmax(POOLED @ wd + bd). One thread/graph.
// ---------------------------------------------------------------------------
__global__ __launch_bounds__(256)
void head_kernel(const float* __restrict__ POOLED, const float* __restrict__ WD,
                 const float* __restrict__ BD, float* __restrict__ OUT)
{
    int g = threadIdx.x;
    float l0 = BD[0], l1 = BD[1];
    #pragma unroll
    for (int k = 0; k < 32; ++k) {
        float p = POOLED[g * 32 + k];
        l0 = fmaf(p, WD[k * 2 + 0], l0);
        l1 = fmaf(p, WD[k * 2 + 1], l1);
    }
    float m = fmaxf(l0, l1);
    float e0 = expf(l0 - m), e1 = expf(l1 - m);
    float s = 1.0f / (e0 + e1);
    OUT[g * 2 + 0] = e0 * s;
    OUT[g * 2 + 1] = e1 * s;
}

extern "C" void kernel_launch(void* const* d_in, const int* in_sizes, int n_in,
                              void* d_out, int out_size, void* d_ws, size_t ws_size,
                              hipStream_t stream)
{
    const float* x    = (const float*)d_in[0];
    const float* ew   = (const float*)d_in[1];
    const int*   er   = (const int*)d_in[2];
    const int*   ec   = (const int*)d_in[3];
    const int*   seg  = (const int*)d_in[4];
    const float* w1_1 = (const float*)d_in[5];
    const float* w2_1 = (const float*)d_in[6];
    const float* b_1  = (const float*)d_in[7];
    const float* w1_2 = (const float*)d_in[8];
    const float* w2_2 = (const float*)d_in[9];
    const float* b_2  = (const float*)d_in[10];
    const float* w1_3 = (const float*)d_in[11];
    const float* w2_3 = (const float*)d_in[12];
    const float* b_3  = (const float*)d_in[13];
    const float* wd   = (const float*)d_in[14];
    const float* bd   = (const float*)d_in[15];

    float* ws = (float*)d_ws;
    // Phase 1 (layer 1): CI = [AX|X] at 0..3.2M, XP at 3.2M..4.8M, H1(B) at 6.4M..12.8M
    float* CI     = ws;                        // N x 64
    float* XP     = ws + 3200000;              // N x 32
    float* B      = ws + 6400000;              // N x 128 (h1)
    // Phase 2 (layer 2): reuse CI/XP region (dead after dense1)
    float* A      = ws;                        // N x 64  (HW1_2)
    float* A2     = ws + 3200000;              // N x 64  (h2 = agg2)
    // Phase 3 (layer 3): reuse B region (dead after dense2)
    float* H3     = ws + 6400000;              // N x 32  (HW1_3)
    float* B2     = ws + 8000000;              // N x 32  (h3 = agg3)
    int*   IW     = (int*)d_ws;
    int*   rowptr = IW + 12800000;             // N+1
    int*   cursor = IW + 12860000;             // N (doubles as deg)
    int2*  packed = (int2*)(IW + 12920000);    // E x {src, wt}  (6.4 MB)
    int*   start  = IW + 14520000;             // G+1
    float* POOLED = ws + 14521000;             // 256 x 32
    int*   bsum   = IW + 14530000;             // NB_SCAN

    hipMemsetAsync(cursor, 0, N_NODES * sizeof(int), stream);

    dim3 blk(256);
    const int MB = (N_NODES + 63) / 64;        // 782
    const int EB4 = (N_EDGES + 1023) / 1024;   // 782 (4 edges/thread)

    // Build CSR (dest-sorted packed edge list) + graph boundaries, every call.
    hist_kernel<<<dim3(EB4), blk, 0, stream>>>(er, cursor);
    blocksum_kernel<<<dim3(NB_SCAN), blk, 0, stream>>>(cursor, bsum);
    bscan_kernel<<<dim3(1), blk, 0, stream>>>(bsum);
    rowptr_kernel<<<dim3(NB_SCAN), blk, 0, stream>>>(cursor, bsum, rowptr, cursor);
    scatter_kernel<<<dim3(EB4), blk, 0, stream>>>(er, ec, ew, cursor, packed);
    bounds_kernel<<<dim3((N_NODES + 255) / 256), blk, 0, stream>>>(seg, start);

    // Layer 1 (pre-aggregation form): CI = [A@X | X], h1 = CI @ [W1;W2] + b
    pad_kernel<<<dim3((N_NODES * 32 + 255) / 256), blk, 0, stream>>>(x, XP, CI);
    aggx_kernel<<<dim3((N_NODES + 31) / 32), blk, 0, stream>>>(XP, rowptr, packed, CI);
    dense1_kernel<<<dim3(MB, 2), blk, 0, stream>>>(CI, w1_1, w2_1, b_1, B);
    // Layer 2: relu(B)(128) -> 64.  HW1 -> A, AGG -> A2, then A2 += A-gather.
    dense_kernel<128, 64><<<dim3(MB, 2), blk, 0, stream>>>(B, w1_2, w2_2, b_2, A, A2, 1);
    spmm_kernel<64><<<dim3((N_NODES + 15) / 16), blk, 0, stream>>>(A, rowptr, packed, A2);
    // Layer 3: relu(A2)(64) -> 32.  HW1 -> H3, AGG -> B2, then B2 += H3-gather.
    dense_kernel<64, 32><<<dim3(MB, 1), blk, 0, stream>>>(A2, w1_3, w2_3, b_3, H3, B2, 1);
    spmm_kernel<32><<<dim3((N_NODES + 31) / 32), blk, 0, stream>>>(H3, rowptr, packed, B2);

    // Pool + head (atomic-free)
    pool_kernel<<<dim3(N_GRAPHS), blk, 0, stream>>>(B2, start, POOLED);
    head_kernel<<<dim3(1), blk, 0, stream>>>(POOLED, wd, bd, (float*)d_out);
}

// Round 7
// 303.944 us; speedup vs baseline: 1.2372x; 1.2372x over previous
//
#include <hip/hip_runtime.h>

#define N_NODES 50000
#define N_EDGES 800000
#define N_GRAPHS 256
#define NCB 196        // coarse buckets = ceil(50000/256), dst>>8
#define CHUNK 3125     // edges per block in coarse passes (256 blocks)
#define GH_LEN (NCB * 256)   // 50176

// ---------------------------------------------------------------------------
// Fused dense: HW1 = act(X) @ W1 ; AGG = act(X) @ W2 + b   (layers 2,3)
// ---------------------------------------------------------------------------
template<int FIN, int FOUT>
__global__ __launch_bounds__(256)
void dense_kernel(const float* __restrict__ X, const float* __restrict__ W1,
                  const float* __restrict__ W2, const float* __restrict__ Bias,
                  float* __restrict__ HW1, float* __restrict__ AGG, int relu_in)
{
    constexpr int KT = (FIN > 64) ? 64 : FIN;
    __shared__ float As[KT * 68];
    __shared__ float Bs[KT * 64];

    const int tid = threadIdx.x;
    const int tm = tid & 15;
    const int tn = tid >> 4;
    const int m0 = blockIdx.x * 64;
    const int c0 = blockIdx.y * 64;

    float acc[4][4];
    #pragma unroll
    for (int i = 0; i < 4; ++i)
        #pragma unroll
        for (int j = 0; j < 4; ++j) acc[i][j] = 0.f;

    for (int kk = 0; kk < FIN; kk += KT) {
        for (int i = tid; i < 64 * KT; i += 256) {
            int n = i / KT;
            int k = i - n * KT;
            int gn = m0 + n;
            float v = 0.f;
            if (gn < N_NODES) v = X[gn * FIN + kk + k];
            if (relu_in) v = fmaxf(v, 0.f);
            As[k * 68 + n] = v;
        }
        for (int i = tid; i < 64 * KT; i += 256) {
            int k = i >> 6;
            int n = i & 63;
            int c = c0 + n;
            float w = (c < FOUT) ? W1[(kk + k) * FOUT + c]
                                 : W2[(kk + k) * FOUT + (c - FOUT)];
            Bs[k * 64 + n] = w;
        }
        __syncthreads();

        #pragma unroll 4
        for (int k = 0; k < KT; ++k) {
            const float4 a = *(const float4*)(As + k * 68 + 4 * tm);
            const float4 b = *(const float4*)(Bs + k * 64 + 4 * tn);
            float av[4] = {a.x, a.y, a.z, a.w};
            float bv[4] = {b.x, b.y, b.z, b.w};
            #pragma unroll
            for (int i = 0; i < 4; ++i)
                #pragma unroll
                for (int j = 0; j < 4; ++j)
                    acc[i][j] = fmaf(av[i], bv[j], acc[i][j]);
        }
        __syncthreads();
    }

    const int c = c0 + 4 * tn;
    const bool w2half = (c >= FOUT);
    float4 bias = make_float4(0.f, 0.f, 0.f, 0.f);
    if (w2half) bias = *(const float4*)(Bias + (c - FOUT));

    #pragma unroll
    for (int i = 0; i < 4; ++i) {
        int gm = m0 + 4 * tm + i;
        if (gm >= N_NODES) continue;
        float4 v = make_float4(acc[i][0] + bias.x, acc[i][1] + bias.y,
                               acc[i][2] + bias.z, acc[i][3] + bias.w);
        if (w2half)
            *(float4*)(AGG + (size_t)gm * FOUT + (c - FOUT)) = v;
        else
            *(float4*)(HW1 + (size_t)gm * FOUT + c) = v;
    }
}

// ---------------------------------------------------------------------------
// Layer-1 dense: h1 = CI @ Wc + b, CI = [A@X pad32 | X pad32] (N x 64)
// ---------------------------------------------------------------------------
__global__ __launch_bounds__(256)
void dense1_kernel(const float* __restrict__ CI, const float* __restrict__ W1,
                   const float* __restrict__ W2, const float* __restrict__ Bias,
                   float* __restrict__ H1)
{
    __shared__ float As[64 * 68];
    __shared__ float Bs[64 * 64];

    const int tid = threadIdx.x;
    const int tm = tid & 15;
    const int tn = tid >> 4;
    const int m0 = blockIdx.x * 64;
    const int c0 = blockIdx.y * 64;

    float acc[4][4];
    #pragma unroll
    for (int i = 0; i < 4; ++i)
        #pragma unroll
        for (int j = 0; j < 4; ++j) acc[i][j] = 0.f;

    for (int i = tid; i < 64 * 64; i += 256) {
        int n = i >> 6;
        int k = i & 63;
        int gn = m0 + n;
        As[k * 68 + n] = (gn < N_NODES) ? CI[(size_t)gn * 64 + k] : 0.f;
    }
    for (int i = tid; i < 64 * 64; i += 256) {
        int k = i >> 6;
        int n = i & 63;
        int c = c0 + n;
        float w = 0.f;
        if (k < 30)       w = W1[k * 128 + c];
        else if (k >= 32 && k < 62) w = W2[(k - 32) * 128 + c];
        Bs[k * 64 + n] = w;
    }
    __syncthreads();

    #pragma unroll 4
    for (int k = 0; k < 64; ++k) {
        const float4 a = *(const float4*)(As + k * 68 + 4 * tm);
        const float4 b = *(const float4*)(Bs + k * 64 + 4 * tn);
        float av[4] = {a.x, a.y, a.z, a.w};
        float bv[4] = {b.x, b.y, b.z, b.w};
        #pragma unroll
        for (int i = 0; i < 4; ++i)
            #pragma unroll
            for (int j = 0; j < 4; ++j)
                acc[i][j] = fmaf(av[i], bv[j], acc[i][j]);
    }

    const int c = c0 + 4 * tn;
    const float4 bias = *(const float4*)(Bias + c);
    #pragma unroll
    for (int i = 0; i < 4; ++i) {
        int gm = m0 + 4 * tm + i;
        if (gm >= N_NODES) continue;
        float4 v = make_float4(acc[i][0] + bias.x, acc[i][1] + bias.y,
                               acc[i][2] + bias.z, acc[i][3] + bias.w);
        *(float4*)(H1 + (size_t)gm * 128 + c) = v;
    }
}

// ---------------------------------------------------------------------------
// CSR build, pass 1a: per-block coarse histogram (dst>>8) into LDS, then
// ghist[bucket*256 + block] (bucket-major for the scan).
// ---------------------------------------------------------------------------
__global__ __launch_bounds__(256)
void c_hist(const int* __restrict__ ER, int* __restrict__ ghist)
{
    __shared__ int h[NCB];
    int t = threadIdx.x, blk = blockIdx.x;
    for (int i = t; i < NCB; i += 256) h[i] = 0;
    __syncthreads();
    int lo = blk * CHUNK, hi = lo + CHUNK;
    for (int e = lo + t; e < hi; e += 256) atomicAdd(&h[ER[e] >> 8], 1);
    __syncthreads();
    for (int i = t; i < NCB; i += 256) ghist[i * 256 + blk] = h[i];
}

// --- 3-phase exclusive scan of ghist (GH_LEN entries) in place -> gofs ---
__global__ __launch_bounds__(256)
void g_blocksum(const int* __restrict__ gh, int* __restrict__ bsum)
{
    __shared__ int red[4];
    int i = blockIdx.x * 256 + threadIdx.x;   // GH_LEN % 256 == 0
    int v = gh[i];
    #pragma unroll
    for (int off = 32; off; off >>= 1) v += __shfl_down(v, off, 64);
    if ((threadIdx.x & 63) == 0) red[threadIdx.x >> 6] = v;
    __syncthreads();
    if (threadIdx.x == 0) bsum[blockIdx.x] = red[0] + red[1] + red[2] + red[3];
}

__global__ __launch_bounds__(256)
void g_bscan(int* __restrict__ bsum)          // exclusive scan of NCB entries
{
    __shared__ int s[256];
    int t = threadIdx.x;
    int v = (t < NCB) ? bsum[t] : 0;
    s[t] = v;
    __syncthreads();
    for (int off = 1; off < 256; off <<= 1) {
        int u = (t >= off) ? s[t - off] : 0;
        __syncthreads();
        s[t] += u;
        __syncthreads();
    }
    if (t < NCB) bsum[t] = s[t] - v;
}

__global__ __launch_bounds__(256)
void g_apply(int* __restrict__ gh, const int* __restrict__ bsum)
{
    __shared__ int s[256];
    int t = threadIdx.x;
    int i = blockIdx.x * 256 + t;
    int v = gh[i];
    s[t] = v;
    __syncthreads();
    for (int off = 1; off < 256; off <<= 1) {
        int u = (t >= off) ? s[t - off] : 0;
        __syncthreads();
        s[t] += u;
        __syncthreads();
    }
    gh[i] = s[t] - v + bsum[blockIdx.x];      // exclusive, in place
}

// ---------------------------------------------------------------------------
// CSR build, pass 1b: coarse scatter. Each block writes its edges into its
// OWN contiguous run per bucket (LDS cursors, no global atomics) -> writes
// stay line-local to one XCD. Record: x = src | ((dst&255)<<16), y = w bits.
// ---------------------------------------------------------------------------
__global__ __launch_bounds__(256)
void c_scatter(const int* __restrict__ ER, const int* __restrict__ EC,
               const float* __restrict__ EW, const int* __restrict__ gofs,
               int2* __restrict__ tmp)
{
    __shared__ int cur[NCB];
    int t = threadIdx.x, blk = blockIdx.x;
    for (int i = t; i < NCB; i += 256) cur[i] = gofs[i * 256 + blk];
    __syncthreads();
    int lo = blk * CHUNK, hi = lo + CHUNK;
    for (int e = lo + t; e < hi; e += 256) {
        int d = ER[e];
        int pos = atomicAdd(&cur[d >> 8], 1);
        tmp[pos] = make_int2(EC[e] | ((d & 255) << 16), __float_as_int(EW[e]));
    }
}

// ---------------------------------------------------------------------------
// CSR build, pass 2: per coarse bucket (196 blocks), counting-sort ~4k edges
// by dst&255 via LDS hist+scan; emit final packed (src,w) dest-sorted AND
// rowptr directly. All global reads/writes coalesced or bucket-local.
// ---------------------------------------------------------------------------
__global__ __launch_bounds__(256)
void bsort(const int2* __restrict__ tmp, const int* __restrict__ gofs,
           int2* __restrict__ packed, int* __restrict__ rowptr)
{
    __shared__ int hist[256];
    __shared__ int s[256];
    __shared__ int cur[256];
    int g = blockIdx.x, t = threadIdx.x;
    int base = gofs[g * 256];
    int end  = (g == NCB - 1) ? N_EDGES : gofs[(g + 1) * 256];
    hist[t] = 0;
    __syncthreads();
    for (int j = base + t; j < end; j += 256)
        atomicAdd(&hist[(tmp[j].x >> 16) & 255], 1);
    __syncthreads();
    int v = hist[t];
    s[t] = v;
    __syncthreads();
    for (int off = 1; off < 256; off <<= 1) {
        int u = (t >= off) ? s[t - off] : 0;
        __syncthreads();
        s[t] += u;
        __syncthreads();
    }
    int excl = s[t] - v;
    int n = g * 256 + t;
    if (n < N_NODES) rowptr[n] = base + excl;
    if (g == NCB - 1 && t == 0) rowptr[N_NODES] = N_EDGES;
    cur[t] = base + excl;
    __syncthreads();
    for (int j = base + t; j < end; j += 256) {
        int2 r = tmp[j];
        int pos = atomicAdd(&cur[(r.x >> 16) & 255], 1);
        packed[pos] = make_int2(r.x & 0xFFFF, r.y);
    }
}

// ---------------------------------------------------------------------------
// pad_kernel: XP[n][c] = (c<30) ? x[n][c] : 0 ; CI[n][32+c] = same
// ---------------------------------------------------------------------------
__global__ __launch_bounds__(256)
void pad_kernel(const float* __restrict__ X, float* __restrict__ XP,
                float* __restrict__ CI)
{
    int idx = blockIdx.x * 256 + threadIdx.x;
    int n = idx >> 5;
    int c = idx & 31;
    if (n >= N_NODES) return;
    float v = (c < 30) ? X[n * 30 + c] : 0.f;
    XP[(size_t)n * 32 + c] = v;
    CI[(size_t)n * 64 + 32 + c] = v;
}

// ---------------------------------------------------------------------------
// aggx_kernel: CI[n][0..31] = sum_j w_j * XP[src_j][0..31]  (A @ X)
// ---------------------------------------------------------------------------
__global__ __launch_bounds__(256)
void aggx_kernel(const float* __restrict__ XP, const int* __restrict__ rowptr,
                 const int2* __restrict__ packed, float* __restrict__ CI)
{
    int tid = threadIdx.x;
    int local = tid >> 3;
    int q = tid & 7;
    int n = blockIdx.x * 32 + local;
    if (n >= N_NODES) return;
    int r0 = rowptr[n], r1 = rowptr[n + 1];
    float4 acc = make_float4(0.f, 0.f, 0.f, 0.f);
    for (int j = r0; j < r1; ++j) {
        int2 r = packed[j];
        float w = __int_as_float(r.y);
        const float4 h = *(const float4*)(XP + (size_t)r.x * 32 + q * 4);
        acc.x = fmaf(w, h.x, acc.x);
        acc.y = fmaf(w, h.y, acc.y);
        acc.z = fmaf(w, h.z, acc.z);
        acc.w = fmaf(w, h.w, acc.w);
    }
    *(float4*)(CI + (size_t)n * 64 + q * 4) = acc;
}

// ---------------------------------------------------------------------------
// Atomic-free SpMM (layers 2,3)
// ---------------------------------------------------------------------------
template<int FOUT>
__global__ __launch_bounds__(256)
void spmm_kernel(const float* __restrict__ HW1, const int* __restrict__ rowptr,
                 const int2* __restrict__ packed, float* __restrict__ AGG)
{
    constexpr int T = FOUT / 4;
    constexpr int NPB = 256 / T;
    int tid = threadIdx.x;
    int local = tid / T;
    int q = tid % T;
    int n = blockIdx.x * NPB + local;
    if (n >= N_NODES) return;
    int r0 = rowptr[n], r1 = rowptr[n + 1];
    float4 acc = *(const float4*)(AGG + (size_t)n * FOUT + q * 4);
    for (int j = r0; j < r1; ++j) {
        int2 r = packed[j];
        float w = __int_as_float(r.y);
        const float4 h = *(const float4*)(HW1 + (size_t)r.x * FOUT + q * 4);
        acc.x = fmaf(w, h.x, acc.x);
        acc.y = fmaf(w, h.y, acc.y);
        acc.z = fmaf(w, h.z, acc.z);
        acc.w = fmaf(w, h.w, acc.w);
    }
    *(float4*)(AGG + (size_t)n * FOUT + q * 4) = acc;
}

// ---------------------------------------------------------------------------
// Graph boundaries from sorted seg
// ---------------------------------------------------------------------------
__global__ __launch_bounds__(256)
void bounds_kernel(const int* __restrict__ SEG, int* __restrict__ start)
{
    int n = blockIdx.x * 256 + threadIdx.x;
    if (n >= N_NODES) return;
    int g = SEG[n];
    int gprev = (n == 0) ? -1 : SEG[n - 1];
    for (int gg = gprev + 1; gg <= g; ++gg) start[gg] = n;
    if (n == N_NODES - 1)
        for (int gg = g + 1; gg <= N_GRAPHS; ++gg) start[gg] = N_NODES;
}

// ---------------------------------------------------------------------------
// Atomic-free pool
// ---------------------------------------------------------------------------
__global__ __launch_bounds__(256)
void pool_kernel(const float* __restrict__ H, const int* __restrict__ start,
                 float* __restrict__ POOLED)
{
    __shared__ float red[8][33];
    int g = blockIdx.x;
    int s = start[g], e = start[g + 1];
    int q = threadIdx.x & 31;
    int lane = threadIdx.x >> 5;
    float acc = 0.f;
    for (int n = s + lane; n < e; n += 8)
        acc += fmaxf(H[(size_t)n * 32 + q], 0.f);
    red[lane][q] = acc;
    __syncthreads();
    if (threadIdx.x < 32) {
        float v = 0.f;
        #pragma unroll
        for (int i = 0; i < 8; ++i) v += red[i][q];
        float inv = (e > s) ? 1.0f / (float)(e - s) : 1.0f;
        POOLED[g * 32 + q] = v * inv;
    }
}

// ---------------------------------------------------------------------------
// Head
// ---------------------------------------------------------------------------
__global__ __launch_bounds__(256)
void head_kernel(const float* __restrict__ POOLED, const float* __restrict__ WD,
                 const float* __restrict__ BD, float* __restrict__ OUT)
{
    int g = threadIdx.x;
    float l0 = BD[0], l1 = BD[1];
    #pragma unroll
    for (int k = 0; k < 32; ++k) {
        float p = POOLED[g * 32 + k];
        l0 = fmaf(p, WD[k * 2 + 0], l0);
        l1 = fmaf(p, WD[k * 2 + 1], l1);
    }
    float m = fmaxf(l0, l1);
    float e0 = expf(l0 - m), e1 = expf(l1 - m);
    float s = 1.0f / (e0 + e1);
    OUT[g * 2 + 0] = e0 * s;
    OUT[g * 2 + 1] = e1 * s;
}

extern "C" void kernel_launch(void* const* d_in, const int* in_sizes, int n_in,
                              void* d_out, int out_size, void* d_ws, size_t ws_size,
                              hipStream_t stream)
{
    const float* x    = (const float*)d_in[0];
    const float* ew   = (const float*)d_in[1];
    const int*   er   = (const int*)d_in[2];
    const int*   ec   = (const int*)d_in[3];
    const int*   seg  = (const int*)d_in[4];
    const float* w1_1 = (const float*)d_in[5];
    const float* w2_1 = (const float*)d_in[6];
    const float* b_1  = (const float*)d_in[7];
    const float* w1_2 = (const float*)d_in[8];
    const float* w2_2 = (const float*)d_in[9];
    const float* b_2  = (const float*)d_in[10];
    const float* w1_3 = (const float*)d_in[11];
    const float* w2_3 = (const float*)d_in[12];
    const float* b_3  = (const float*)d_in[13];
    const float* wd   = (const float*)d_in[14];
    const float* bd   = (const float*)d_in[15];

    float* ws = (float*)d_ws;
    // Phase 1 (layer 1): CI 0..3.2M, XP 3.2..4.8M, B(h1) 6.4..12.8M
    float* CI     = ws;                        // N x 64
    float* XP     = ws + 3200000;              // N x 32
    float* B      = ws + 6400000;              // N x 128 (h1)
    // tmp (coarse-sorted records) lives inside the B region during CSR build;
    // dead before dense1 writes B.
    int2*  tmp    = (int2*)(ws + 6400000);     // E x int2 (6.4 MB)
    // Phase 2: A 0.., A2 3.2M..; Phase 3: H3 6.4M.., B2 8.0M..
    float* A      = ws;                        // N x 64  (HW1_2)
    float* A2     = ws + 3200000;              // N x 64  (h2)
    float* H3     = ws + 6400000;              // N x 32  (HW1_3)
    float* B2     = ws + 8000000;              // N x 32  (h3)
    int*   IW     = (int*)d_ws;
    int2*  packed = (int2*)(IW + 12800000);    // E x {src, w}  (6.4 MB)
    int*   rowptr = IW + 14400000;             // N+1
    int*   gofs   = IW + 14460000;             // GH_LEN (ghist -> scanned in place)
    int*   bsum   = IW + 14515000;             // NCB
    int*   start  = IW + 14520000;             // G+1
    float* POOLED = ws + 14525000;             // 256 x 32

    dim3 blk(256);
    const int MB = (N_NODES + 63) / 64;        // 782

    // ---- CSR build: locality-preserving two-pass counting sort ----
    c_hist<<<dim3(256), blk, 0, stream>>>(er, gofs);
    g_blocksum<<<dim3(GH_LEN / 256), blk, 0, stream>>>(gofs, bsum);
    g_bscan<<<dim3(1), blk, 0, stream>>>(bsum);
    g_apply<<<dim3(GH_LEN / 256), blk, 0, stream>>>(gofs, bsum);
    c_scatter<<<dim3(256), blk, 0, stream>>>(er, ec, ew, gofs, tmp);
    bsort<<<dim3(NCB), blk, 0, stream>>>(tmp, gofs, packed, rowptr);
    bounds_kernel<<<dim3((N_NODES + 255) / 256), blk, 0, stream>>>(seg, start);

    // Layer 1 (pre-aggregation form): CI = [A@X | X], h1 = CI @ [W1;W2] + b
    pad_kernel<<<dim3((N_NODES * 32 + 255) / 256), blk, 0, stream>>>(x, XP, CI);
    aggx_kernel<<<dim3((N_NODES + 31) / 32), blk, 0, stream>>>(XP, rowptr, packed, CI);
    dense1_kernel<<<dim3(MB, 2), blk, 0, stream>>>(CI, w1_1, w2_1, b_1, B);
    // Layer 2: relu(B)(128) -> 64
    dense_kernel<128, 64><<<dim3(MB, 2), blk, 0, stream>>>(B, w1_2, w2_2, b_2, A, A2, 1);
    spmm_kernel<64><<<dim3((N_NODES + 15) / 16), blk, 0, stream>>>(A, rowptr, packed, A2);
    // Layer 3: relu(A2)(64) -> 32
    dense_kernel<64, 32><<<dim3(MB, 1), blk, 0, stream>>>(A2, w1_3, w2_3, b_3, H3, B2, 1);
    spmm_kernel<32><<<dim3((N_NODES + 31) / 32), blk, 0, stream>>>(H3, rowptr, packed, B2);

    // Pool + head (atomic-free)
    pool_kernel<<<dim3(N_GRAPHS), blk, 0, stream>>>(B2, start, POOLED);
    head_kernel<<<dim3(1), blk, 0, stream>>>(POOLED, wd, bd, (float*)d_out);
}